// Round 11
// baseline (243.403 us; speedup 1.0000x reference)
//
#include <hip/hip_runtime.h>
#include <hip/hip_bf16.h>
#include <cstdint>

#define NN 50000
#define NE 800000
#define HD 128
#define OD 64
#define NG 64
#define NBUCK 196          // buckets of 256 dst nodes
#define SCHUNK 4096        // edges per scatter block
#define SBLOCKS 196        // ceil(800000/4096)
#define CSR_CAP 5120       // per-bucket capacity (mean 4082, +16 sigma)
#define GEMM_BLOCKS 782    // ceil(50000/64)
#define AGG_NB 12500       // node-blocks per slice (4 nodes each)

typedef unsigned int uint32;
typedef unsigned short u16;
typedef _Float16 f16;
typedef _Float16 f16x8 __attribute__((ext_vector_type(8)));
typedef float f32x4 __attribute__((ext_vector_type(4)));

static __device__ __forceinline__ u16 f2h(float f) {
    f16 h = (f16)f;                       // v_cvt_f16_f32, RTNE
    return __builtin_bit_cast(u16, h);
}
static __device__ __forceinline__ float h2f(u16 u) {
    return (float)__builtin_bit_cast(f16, u);
}
static __device__ __forceinline__ uint32 pkh2(float x, float y) {
    return (uint32)f2h(x) | ((uint32)f2h(y) << 16);
}
static __device__ __forceinline__ void acc_h2f2(float2& a, uint32 u) {
    a.x += h2f((u16)(u & 0xffffu));
    a.y += h2f((u16)(u >> 16));
}
static __device__ __forceinline__ void add8(float* a, uint4 m) {
    a[0] += h2f((u16)(m.x & 0xffffu)); a[1] += h2f((u16)(m.x >> 16));
    a[2] += h2f((u16)(m.y & 0xffffu)); a[3] += h2f((u16)(m.y >> 16));
    a[4] += h2f((u16)(m.z & 0xffffu)); a[5] += h2f((u16)(m.z >> 16));
    a[6] += h2f((u16)(m.w & 0xffffu)); a[7] += h2f((u16)(m.w >> 16));
}
// epilogue LDS transpose swizzle (involution, 16B-granular)
static __device__ __forceinline__ int swz(int row) {
    return ((row & 7) << 4) | ((row & 8) << 3);
}

// Sliced feature layout: uint4 index ((slice*NN + v)*4 + sub), slice=c>>5, sub=(c&31)>>3.

// ---------- prep: pack W1,W2 to fp16 frag order; zero bucket_fill + pooled ----------
// sigma: k = ks*32 + (lane>>4)*8 + j ; n = ct*16 + (lane&15); A,B share sigma.

__global__ __launch_bounds__(256) void k_prep(const float* __restrict__ W1,
                                              const float* __restrict__ W2,
                                              u16* __restrict__ pw1,
                                              u16* __restrict__ pw2,
                                              int* __restrict__ bucket_fill,
                                              float* __restrict__ pooled) {
    int b = blockIdx.x, t = threadIdx.x;
    if (b == 16) {
        if (t < NBUCK) bucket_fill[t] = 0;
        float4 z = make_float4(0.f, 0.f, 0.f, 0.f);
#pragma unroll
        for (int i = 0; i < 8; ++i) ((float4*)pooled)[i * 256 + t] = z;
        return;
    }
    const float* W = (b < 8) ? W1 : W2;
    u16* pw = (b < 8) ? pw1 : pw2;
    int tau = (b & 7) * 256 + t;                // 0..2047
    int lane = tau & 63, ct = (tau >> 6) & 7, ks = (tau >> 9) & 3;
    int g = lane >> 4, n = ct * 16 + (lane & 15);
    uint32 pk[4];
#pragma unroll
    for (int jp = 0; jp < 4; ++jp) {
        int k = ks * 32 + g * 8 + jp * 2;
        uint32 lo = f2h(W[k * 128 + n]);
        uint32 hi = f2h(W[(k + 1) * 128 + n]);
        pk[jp] = lo | (hi << 16);
    }
    ((uint4*)pw)[(size_t)((ks * 8 + ct) * 64 + lane)] = make_uint4(pk[0], pk[1], pk[2], pk[3]);
}

// ---------- single-pass bucketed scatter into fixed-capacity strided buckets ----------

__global__ __launch_bounds__(256) void k_scatter(const int* __restrict__ src,
                                                 const int* __restrict__ dst,
                                                 int* __restrict__ bucket_fill,
                                                 uint32* __restrict__ grec) {
    __shared__ uint32 rin[SCHUNK];
    __shared__ uint32 rout[SCHUNK];
    __shared__ int lh[256], ls[256], lf[256], lgb[256];
    int t = threadIdx.x;
    lh[t] = 0; lf[t] = 0;
    __syncthreads();
    int e0 = blockIdx.x * SCHUNK;
    int ne = min(SCHUNK, NE - e0);
    for (int k = 0; k < 16; ++k) {
        int i = k * 256 + t;
        if (i < ne) {
            uint32 rec = ((uint32)dst[e0 + i] << 16) | (uint32)src[e0 + i];
            rin[i] = rec;
            atomicAdd(&lh[rec >> 24], 1);
        }
    }
    __syncthreads();
    int v = lh[t];
    ls[t] = v; __syncthreads();
    for (int off = 1; off < 256; off <<= 1) {
        int u = (t >= off) ? ls[t - off] : 0;
        __syncthreads();
        ls[t] += u;
        __syncthreads();
    }
    int excl = ls[t] - v;
    __syncthreads();
    ls[t] = excl;
    if (t < NBUCK && v > 0) lgb[t] = atomicAdd(&bucket_fill[t], v);
    __syncthreads();
    for (int k = 0; k < 16; ++k) {
        int i = k * 256 + t;
        if (i < ne) {
            uint32 rec = rin[i];
            int b = rec >> 24;
            int p = ls[b] + atomicAdd(&lf[b], 1);
            rout[p] = rec;
        }
    }
    __syncthreads();
    for (int k = 0; k < 16; ++k) {
        int i = k * 256 + t;
        if (i < ne) {
            uint32 rec = rout[i];
            int b = rec >> 24;
            int pos = lgb[b] + (i - ls[b]);
            if (pos < CSR_CAP) grec[(size_t)b * CSR_CAP + pos] = rec;
        }
    }
}

// ---------- per-bucket counting sort -> u16 CSR + packed (rs|deg<<20) + dinv ----------

__global__ __launch_bounds__(256) void k_csr(const uint32* __restrict__ grec,
                                             const int* __restrict__ bucket_fill,
                                             uint32* __restrict__ packed,
                                             float* __restrict__ dinv,
                                             u16* __restrict__ csr) {
    __shared__ uint32 rin[CSR_CAP];
    __shared__ u16 sorted[CSR_CAP];
    __shared__ int cnt_l[256], off_l[256], fill_l[256];
    const int b = blockIdx.x, t = threadIdx.x;
    const int s0 = b * CSR_CAP;
    const int n = min(bucket_fill[b], CSR_CAP);
    cnt_l[t] = 0; fill_l[t] = 0;
    __syncthreads();
    for (int i = t; i < n; i += 256) {
        uint32 r = grec[s0 + i];
        rin[i] = r;
        atomicAdd(&cnt_l[(r >> 16) & 255], 1);
    }
    __syncthreads();
    int v = cnt_l[t];
    off_l[t] = v; __syncthreads();
    for (int off = 1; off < 256; off <<= 1) {
        int u = (t >= off) ? off_l[t - off] : 0;
        __syncthreads();
        off_l[t] += u;
        __syncthreads();
    }
    int excl = off_l[t] - v;
    __syncthreads();
    off_l[t] = excl;
    int vtx = (b << 8) + t;
    if (vtx < NN) {
        packed[vtx] = (uint32)(s0 + excl) | ((uint32)v << 20);
        dinv[vtx] = rsqrtf((float)(v + 1));   // +1 self-loop
    }
    __syncthreads();
    for (int i = t; i < n; i += 256) {
        uint32 r = rin[i];
        int d = (r >> 16) & 255;
        int p = off_l[d] + atomicAdd(&fill_l[d], 1);
        sorted[p] = (u16)(r & 0xffffu);
    }
    __syncthreads();
    for (int i = t; i < n; i += 256) csr[s0 + i] = sorted[i];
}

// ---------- MFMA GEMM (fp32 input): hp = f16((X @ W) * dinv), sliced output ----------

__global__ __launch_bounds__(256, 2) void k_gemm_f32(const float* __restrict__ X,
                                                     const u16* __restrict__ pw,
                                                     const float* __restrict__ dinv,
                                                     u16* __restrict__ hp, int nrows) {
    __shared__ u16 xp[8192];    // 16 KB A-frags, reused for epilogue
    const int t = threadIdx.x, lane = t & 63, wv = t >> 6;
    const int r0 = blockIdx.x * 64;
    const float4* X4 = (const float4*)X;
#pragma unroll
    for (int it = 0; it < 8; ++it) {
        int idx = it * 256 + t;          // 64 rows x 32 float4-cols
        int rloc = idx >> 5, kq = idx & 31;
        int rr = r0 + rloc;
        float4 xv = (rr < nrows) ? X4[(size_t)rr * 32 + kq]
                                 : make_float4(0.f, 0.f, 0.f, 0.f);
        int ks = kq >> 3, g = (kq >> 1) & 3, half = kq & 1;
        int wvd = rloc >> 4, ln = (rloc & 15) + 16 * g;
        ushort4 p;
        p.x = f2h(xv.x); p.y = f2h(xv.y); p.z = f2h(xv.z); p.w = f2h(xv.w);
        *(ushort4*)&xp[(((ks * 4 + wvd) * 64 + ln) << 3) + half * 4] = p;
    }
    __syncthreads();
    f32x4 acc[8];
#pragma unroll
    for (int c = 0; c < 8; ++c) acc[c] = (f32x4){0.f, 0.f, 0.f, 0.f};
#pragma unroll
    for (int ks = 0; ks < 4; ++ks) {
        f16x8 a = *reinterpret_cast<f16x8*>(&xp[((ks * 4 + wv) * 64 + lane) << 3]);
#pragma unroll
        for (int ct = 0; ct < 8; ++ct) {
            f16x8 b = *reinterpret_cast<const f16x8*>(pw + ((size_t)((ks * 8 + ct) * 64 + lane) << 3));
            acc[ct] = __builtin_amdgcn_mfma_f32_16x16x32_f16(a, b, acc[ct], 0, 0, 0);
        }
    }
    float dv[4];
#pragma unroll
    for (int r = 0; r < 4; ++r) {
        int m = r0 + wv * 16 + 4 * (lane >> 4) + r;
        dv[r] = (m < nrows) ? dinv[m] : 0.f;
    }
    __syncthreads();
#pragma unroll
    for (int ct = 0; ct < 8; ++ct)
#pragma unroll
        for (int r = 0; r < 4; ++r) {
            int row_local = wv * 16 + 4 * (lane >> 4) + r;
            int colb = ct * 32 + (lane & 15) * 2;
            int byte = row_local * 256 + (colb ^ swz(row_local));
            xp[byte >> 1] = f2h(acc[ct][r] * dv[r]);
        }
    __syncthreads();
#pragma unroll
    for (int p = 0; p < 4; ++p) {
        int row_local = t >> 2;
        int chunk = (t & 3) + 4 * p;   // slice = p, sub = t&3
        int byte = row_local * 256 + ((chunk * 16) ^ swz(row_local));
        uint4 val = *reinterpret_cast<uint4*>(&xp[byte >> 1]);
        int rr = r0 + row_local;
        if (rr < nrows)
            ((uint4*)hp)[((size_t)p * NN + rr) * 4 + (t & 3)] = val;
    }
}

// ---------- MFMA GEMM (f16 sliced input): hp = f16((Xh @ W) * dinv), sliced output ----------

__global__ __launch_bounds__(256, 2) void k_gemm_f16(const u16* __restrict__ Xh,
                                                     const u16* __restrict__ pw,
                                                     const float* __restrict__ dinv,
                                                     u16* __restrict__ hp, int nrows) {
    __shared__ u16 xp[8192];
    const int t = threadIdx.x, lane = t & 63, wv = t >> 6;
    const int r0 = blockIdx.x * 64;
    const uint4* X16 = (const uint4*)Xh;
#pragma unroll
    for (int it = 0; it < 4; ++it) {
        int idx = it * 256 + t;          // 64 rows x 16 16B-chunks
        int rloc = idx >> 4, c = idx & 15;
        int rr = r0 + rloc;
        uint4 v = (rr < nrows) ? X16[((size_t)(c >> 2) * NN + rr) * 4 + (c & 3)]
                               : make_uint4(0u, 0u, 0u, 0u);
        int ks = c >> 2, g = c & 3;
        int wvd = rloc >> 4, ln = (rloc & 15) + 16 * g;
        *(uint4*)&xp[((ks * 4 + wvd) * 64 + ln) << 3] = v;
    }
    __syncthreads();
    f32x4 acc[8];
#pragma unroll
    for (int c = 0; c < 8; ++c) acc[c] = (f32x4){0.f, 0.f, 0.f, 0.f};
#pragma unroll
    for (int ks = 0; ks < 4; ++ks) {
        f16x8 a = *reinterpret_cast<f16x8*>(&xp[((ks * 4 + wv) * 64 + lane) << 3]);
#pragma unroll
        for (int ct = 0; ct < 8; ++ct) {
            f16x8 b = *reinterpret_cast<const f16x8*>(pw + ((size_t)((ks * 8 + ct) * 64 + lane) << 3));
            acc[ct] = __builtin_amdgcn_mfma_f32_16x16x32_f16(a, b, acc[ct], 0, 0, 0);
        }
    }
    float dv[4];
#pragma unroll
    for (int r = 0; r < 4; ++r) {
        int m = r0 + wv * 16 + 4 * (lane >> 4) + r;
        dv[r] = (m < nrows) ? dinv[m] : 0.f;
    }
    __syncthreads();
#pragma unroll
    for (int ct = 0; ct < 8; ++ct)
#pragma unroll
        for (int r = 0; r < 4; ++r) {
            int row_local = wv * 16 + 4 * (lane >> 4) + r;
            int colb = ct * 32 + (lane & 15) * 2;
            int byte = row_local * 256 + (colb ^ swz(row_local));
            xp[byte >> 1] = f2h(acc[ct][r] * dv[r]);
        }
    __syncthreads();
#pragma unroll
    for (int p = 0; p < 4; ++p) {
        int row_local = t >> 2;
        int chunk = (t & 3) + 4 * p;
        int byte = row_local * 256 + ((chunk * 16) ^ swz(row_local));
        uint4 val = *reinterpret_cast<uint4*>(&xp[byte >> 1]);
        int rr = r0 + row_local;
        if (rr < nrows)
            ((uint4*)hp)[((size_t)p * NN + rr) * 4 + (t & 3)] = val;
    }
}

// ---------- sliced aggregation: slice = blockIdx/12500 (phase-ordered for L2 residency) ----
// wave = 1 node x 1 slice; 16 edge slots x 4 lanes x 16B -> full 64B slice row per edge.

__global__ __launch_bounds__(256) void k_aggs(const uint32* __restrict__ hp,
                                              const uint32* __restrict__ packed,
                                              const u16* __restrict__ csr,
                                              const float* __restrict__ dinv,
                                              const float* __restrict__ bias,
                                              uint32* __restrict__ outh) {
    const int p = blockIdx.x / AGG_NB;
    const int nb = blockIdx.x - p * AGG_NB;
    const int lane = threadIdx.x & 63;
    const int v = nb * 4 + (threadIdx.x >> 6);        // NN = 4*AGG_NB exactly
    const int slot = lane >> 2, sub = lane & 3;
    const uint4* base = (const uint4*)hp + (size_t)p * NN * 4;

    float acc[8];
#pragma unroll
    for (int j = 0; j < 8; ++j) acc[j] = 0.f;

    if (slot == 0) {                                   // self loop, once per sub
        add8(acc, base[(size_t)v * 4 + sub]);
    }
    uint32 pk = packed[v];
    const int e0 = (int)(pk & 0xFFFFFu);
    const int end = e0 + (int)(pk >> 20);
    int idx = e0 + slot;
    for (; idx + 16 < end; idx += 32) {                // 32 edges in flight per wave
        int s0 = csr[idx], s1 = csr[idx + 16];
        uint4 m0 = base[(size_t)s0 * 4 + sub];
        uint4 m1 = base[(size_t)s1 * 4 + sub];
        add8(acc, m0); add8(acc, m1);
    }
    for (; idx < end; idx += 16) {
        int s = csr[idx];
        add8(acc, base[(size_t)s * 4 + sub]);
    }
#pragma unroll
    for (int j = 0; j < 8; ++j) {                      // reduce over 16 slots (bits 2..5)
        acc[j] += __shfl_xor(acc[j], 4, 64);
        acc[j] += __shfl_xor(acc[j], 8, 64);
        acc[j] += __shfl_xor(acc[j], 16, 64);
        acc[j] += __shfl_xor(acc[j], 32, 64);
    }
    if (slot == 0) {
        float dvv = dinv[v];
        const float4* b4 = (const float4*)bias;
        float4 ba = b4[p * 8 + sub * 2];
        float4 bb = b4[p * 8 + sub * 2 + 1];
        uint4 o;
        o.x = pkh2(fmaxf(acc[0] * dvv + ba.x, 0.f), fmaxf(acc[1] * dvv + ba.y, 0.f));
        o.y = pkh2(fmaxf(acc[2] * dvv + ba.z, 0.f), fmaxf(acc[3] * dvv + ba.w, 0.f));
        o.z = pkh2(fmaxf(acc[4] * dvv + bb.x, 0.f), fmaxf(acc[5] * dvv + bb.y, 0.f));
        o.w = pkh2(fmaxf(acc[6] * dvv + bb.z, 0.f), fmaxf(acc[7] * dvv + bb.w, 0.f));
        ((uint4*)outh)[((size_t)p * NN + v) * 4 + sub] = o;
    }
}

// ---------- pooling stage 1: sliced f16 in, fp32 segment-sum into pooled[64][128] ----------

__global__ __launch_bounds__(256) void k_pool1(const uint32* __restrict__ h,
                                               const int* __restrict__ batch,
                                               float* __restrict__ pooled) {
    __shared__ int bl[256];
    const int row0 = blockIdx.x * 256;
    const int rend = min(row0 + 256, NN);
    const int nrows = rend - row0;
    for (int i = threadIdx.x; i < nrows; i += 256) bl[i] = batch[row0 + i];
    __syncthreads();
    const int col2 = threadIdx.x & 63;      // uint column (2 fp16 cols)
    const int rp   = threadIdx.x >> 6;
    const size_t sbase = (size_t)(col2 >> 4) * NN * 16;  // slice base (uint units)
    const int soff = col2 & 15;
    float2 acc = make_float2(0.f, 0.f);
    int curg = -1;
    for (int i = rp; i < nrows; i += 4) {
        int g = bl[i];
        if (g != curg) {
            if (curg >= 0) {
                atomicAdd(&pooled[curg * 128 + 2 * col2], acc.x);
                atomicAdd(&pooled[curg * 128 + 2 * col2 + 1], acc.y);
            }
            acc = make_float2(0.f, 0.f);
            curg = g;
        }
        acc_h2f2(acc, h[sbase + (size_t)(row0 + i) * 16 + soff]);
    }
    if (curg >= 0) {
        atomicAdd(&pooled[curg * 128 + 2 * col2], acc.x);
        atomicAdd(&pooled[curg * 128 + 2 * col2 + 1], acc.y);
    }
}

// ---------- mean + linear head ----------

__global__ __launch_bounds__(256) void k_head(const float* __restrict__ pooled,
                                              const int* __restrict__ batch,
                                              const float* __restrict__ Wl,
                                              const float* __restrict__ bl_,
                                              float* __restrict__ out) {
    int g = blockIdx.x, t = threadIdx.x;
    __shared__ int se[2];
    __shared__ float pm[128];
    __shared__ float part[256];
    if (t < 2) {
        int target = g + t;
        int lo = 0, hi = NN;
        while (lo < hi) {
            int mid = (lo + hi) >> 1;
            if (batch[mid] < target) lo = mid + 1; else hi = mid;
        }
        se[t] = lo;
    }
    __syncthreads();
    int cntg = se[1] - se[0];
    float inv = 1.f / (float)(cntg > 0 ? cntg : 1);
    if (t < 128) pm[t] = pooled[g * 128 + t] * inv;
    __syncthreads();
    int col = t & 63, kh = t >> 6;
    float o = 0.f;
    for (int k = kh * 32; k < kh * 32 + 32; ++k) o += pm[k] * Wl[k * OD + col];
    part[t] = o; __syncthreads();
    if (t < OD)
        out[g * OD + t] = part[t] + part[t + 64] + part[t + 128] + part[t + 192] + bl_[t];
}

// ---------- launcher ----------

extern "C" void kernel_launch(void* const* d_in, const int* in_sizes, int n_in,
                              void* d_out, int out_size, void* d_ws, size_t ws_size,
                              hipStream_t stream) {
    const float* x   = (const float*)d_in[0];
    const int*   ei  = (const int*)d_in[1];
    const int*   bat = (const int*)d_in[2];
    const float* W1  = (const float*)d_in[3];
    const float* b1  = (const float*)d_in[4];
    const float* W2  = (const float*)d_in[5];
    const float* b2  = (const float*)d_in[6];
    const float* Wl  = (const float*)d_in[7];
    const float* bl  = (const float*)d_in[8];
    float* out = (float*)d_out;
    const int* src = ei;
    const int* dst = ei + NE;

    char* w = (char*)d_ws;
    size_t off = 0;
    auto alloc = [&](size_t bytes) -> char* {
        char* p = w + off;
        off = (off + bytes + 255) & ~(size_t)255;
        return p;
    };
    float*  dinv        = (float*)alloc(NN * 4);
    uint32* packed      = (uint32*)alloc(NN * 4);
    int*    bucket_fill = (int*)alloc(NBUCK * 4);
    float*  pooled      = (float*)alloc(NG * HD * 4);
    u16*    pw1         = (u16*)alloc(2048 * 16);
    u16*    pw2         = (u16*)alloc(2048 * 16);
    uint32* grec        = (uint32*)alloc((size_t)NBUCK * CSR_CAP * 4);
    u16*    csr         = (u16*)alloc((size_t)NBUCK * CSR_CAP * 2);
    u16*    hp          = (u16*)alloc((size_t)NN * HD * 2);   // f16 h' (sliced)
    u16*    h2          = (u16*)alloc((size_t)NN * HD * 2);   // f16 layer out (sliced)

    k_prep<<<17, 256, 0, stream>>>(W1, W2, pw1, pw2, bucket_fill, pooled);
    k_scatter<<<SBLOCKS, 256, 0, stream>>>(src, dst, bucket_fill, grec);
    k_csr<<<NBUCK, 256, 0, stream>>>(grec, bucket_fill, packed, dinv, csr);

    // conv1
    k_gemm_f32<<<GEMM_BLOCKS, 256, 0, stream>>>(x, pw1, dinv, hp, NN);
    k_aggs<<<4 * AGG_NB, 256, 0, stream>>>((const uint32*)hp, packed, csr, dinv, b1, (uint32*)h2);
    // conv2
    k_gemm_f16<<<GEMM_BLOCKS, 256, 0, stream>>>(h2, pw2, dinv, hp, NN);
    k_aggs<<<4 * AGG_NB, 256, 0, stream>>>((const uint32*)hp, packed, csr, dinv, b2, (uint32*)h2);
    // pool + head
    k_pool1<<<(NN + 255) / 256, 256, 0, stream>>>((const uint32*)h2, bat, pooled);
    k_head<<<NG, 256, 0, stream>>>(pooled, bat, Wl, bl, out);
}

// Round 12
// 152.019 us; speedup vs baseline: 1.6011x; 1.6011x over previous
//
#include <hip/hip_runtime.h>
#include <hip/hip_bf16.h>
#include <cstdint>

#define NN 50000
#define NE 800000
#define HD 128
#define OD 64
#define NG 64
#define NBUCK 196          // buckets of 256 dst nodes
#define SCHUNK 4096        // edges per scatter block
#define SBLOCKS 196        // ceil(800000/4096)
#define CSR_CAP 5120       // per-bucket capacity (mean 4082, +16 sigma)
#define GEMM_BLOCKS 782    // ceil(50000/64)

typedef unsigned int uint32;
typedef unsigned short u16;
typedef _Float16 f16;
typedef _Float16 f16x8 __attribute__((ext_vector_type(8)));
typedef float f32x4 __attribute__((ext_vector_type(4)));

static __device__ __forceinline__ u16 f2h(float f) {
    f16 h = (f16)f;                       // v_cvt_f16_f32, RTNE
    return __builtin_bit_cast(u16, h);
}
static __device__ __forceinline__ float h2f(u16 u) {
    return (float)__builtin_bit_cast(f16, u);
}
static __device__ __forceinline__ void acc_h2(float2& a, uint32 u) {
    a.x += h2f((u16)(u & 0xffffu));
    a.y += h2f((u16)(u >> 16));
}
static __device__ __forceinline__ uint32 pkh2(float x, float y) {
    return (uint32)f2h(x) | ((uint32)f2h(y) << 16);
}
// epilogue LDS transpose swizzle (involution, 16B-granular)
static __device__ __forceinline__ int swz(int row) {
    return ((row & 7) << 4) | ((row & 8) << 3);
}

// ---------- prep: pack W1,W2 to fp16 frag order; zero bucket_fill + pooled ----------
// sigma: k = ks*32 + (lane>>4)*8 + j ; n = ct*16 + (lane&15); A,B share sigma.

__global__ __launch_bounds__(256) void k_prep(const float* __restrict__ W1,
                                              const float* __restrict__ W2,
                                              u16* __restrict__ pw1,
                                              u16* __restrict__ pw2,
                                              int* __restrict__ bucket_fill,
                                              float* __restrict__ pooled) {
    int b = blockIdx.x, t = threadIdx.x;
    if (b == 16) {
        if (t < NBUCK) bucket_fill[t] = 0;
        float4 z = make_float4(0.f, 0.f, 0.f, 0.f);
#pragma unroll
        for (int i = 0; i < 8; ++i) ((float4*)pooled)[i * 256 + t] = z;
        return;
    }
    const float* W = (b < 8) ? W1 : W2;
    u16* pw = (b < 8) ? pw1 : pw2;
    int tau = (b & 7) * 256 + t;                // 0..2047
    int lane = tau & 63, ct = (tau >> 6) & 7, ks = (tau >> 9) & 3;
    int g = lane >> 4, n = ct * 16 + (lane & 15);
    uint32 pk[4];
#pragma unroll
    for (int jp = 0; jp < 4; ++jp) {
        int k = ks * 32 + g * 8 + jp * 2;
        uint32 lo = f2h(W[k * 128 + n]);
        uint32 hi = f2h(W[(k + 1) * 128 + n]);
        pk[jp] = lo | (hi << 16);
    }
    ((uint4*)pw)[(size_t)((ks * 8 + ct) * 64 + lane)] = make_uint4(pk[0], pk[1], pk[2], pk[3]);
}

// ---------- single-pass bucketed scatter into fixed-capacity strided buckets ----------

__global__ __launch_bounds__(256) void k_scatter(const int* __restrict__ src,
                                                 const int* __restrict__ dst,
                                                 int* __restrict__ bucket_fill,
                                                 uint32* __restrict__ grec) {
    __shared__ uint32 rin[SCHUNK];
    __shared__ uint32 rout[SCHUNK];
    __shared__ int lh[256], ls[256], lf[256], lgb[256];
    int t = threadIdx.x;
    lh[t] = 0; lf[t] = 0;
    __syncthreads();
    int e0 = blockIdx.x * SCHUNK;
    int ne = min(SCHUNK, NE - e0);
    for (int k = 0; k < 16; ++k) {
        int i = k * 256 + t;
        if (i < ne) {
            uint32 rec = ((uint32)dst[e0 + i] << 16) | (uint32)src[e0 + i];
            rin[i] = rec;
            atomicAdd(&lh[rec >> 24], 1);
        }
    }
    __syncthreads();
    int v = lh[t];
    ls[t] = v; __syncthreads();
    for (int off = 1; off < 256; off <<= 1) {
        int u = (t >= off) ? ls[t - off] : 0;
        __syncthreads();
        ls[t] += u;
        __syncthreads();
    }
    int excl = ls[t] - v;
    __syncthreads();
    ls[t] = excl;
    if (t < NBUCK && v > 0) lgb[t] = atomicAdd(&bucket_fill[t], v);
    __syncthreads();
    for (int k = 0; k < 16; ++k) {
        int i = k * 256 + t;
        if (i < ne) {
            uint32 rec = rin[i];
            int b = rec >> 24;
            int p = ls[b] + atomicAdd(&lf[b], 1);
            rout[p] = rec;
        }
    }
    __syncthreads();
    for (int k = 0; k < 16; ++k) {
        int i = k * 256 + t;
        if (i < ne) {
            uint32 rec = rout[i];
            int b = rec >> 24;
            int pos = lgb[b] + (i - ls[b]);
            if (pos < CSR_CAP) grec[(size_t)b * CSR_CAP + pos] = rec;
        }
    }
}

// ---------- per-bucket counting sort -> u16 CSR + packed (rs|deg<<20) + dinv ----------

__global__ __launch_bounds__(256) void k_csr(const uint32* __restrict__ grec,
                                             const int* __restrict__ bucket_fill,
                                             uint32* __restrict__ packed,
                                             float* __restrict__ dinv,
                                             u16* __restrict__ csr) {
    __shared__ uint32 rin[CSR_CAP];
    __shared__ u16 sorted[CSR_CAP];
    __shared__ int cnt_l[256], off_l[256], fill_l[256];
    const int b = blockIdx.x, t = threadIdx.x;
    const int s0 = b * CSR_CAP;
    const int n = min(bucket_fill[b], CSR_CAP);
    cnt_l[t] = 0; fill_l[t] = 0;
    __syncthreads();
    for (int i = t; i < n; i += 256) {
        uint32 r = grec[s0 + i];
        rin[i] = r;
        atomicAdd(&cnt_l[(r >> 16) & 255], 1);
    }
    __syncthreads();
    int v = cnt_l[t];
    off_l[t] = v; __syncthreads();
    for (int off = 1; off < 256; off <<= 1) {
        int u = (t >= off) ? off_l[t - off] : 0;
        __syncthreads();
        off_l[t] += u;
        __syncthreads();
    }
    int excl = off_l[t] - v;
    __syncthreads();
    off_l[t] = excl;
    int vtx = (b << 8) + t;
    if (vtx < NN) {
        packed[vtx] = (uint32)(s0 + excl) | ((uint32)v << 20);
        dinv[vtx] = rsqrtf((float)(v + 1));   // +1 self-loop
    }
    __syncthreads();
    for (int i = t; i < n; i += 256) {
        uint32 r = rin[i];
        int d = (r >> 16) & 255;
        int p = off_l[d] + atomicAdd(&fill_l[d], 1);
        sorted[p] = (u16)(r & 0xffffu);
    }
    __syncthreads();
    for (int i = t; i < n; i += 256) csr[s0 + i] = sorted[i];
}

// ---------- MFMA GEMM (fp32 input): hp = f16((X @ W) * dinv) ----------

__global__ __launch_bounds__(256, 2) void k_gemm_f32(const float* __restrict__ X,
                                                     const u16* __restrict__ pw,
                                                     const float* __restrict__ dinv,
                                                     u16* __restrict__ hp, int nrows) {
    __shared__ u16 xp[8192];    // 16 KB A-frags, reused for epilogue
    const int t = threadIdx.x, lane = t & 63, wv = t >> 6;
    const int r0 = blockIdx.x * 64;
    const float4* X4 = (const float4*)X;
#pragma unroll
    for (int it = 0; it < 8; ++it) {
        int idx = it * 256 + t;          // 64 rows x 32 float4-cols
        int rloc = idx >> 5, kq = idx & 31;
        int rr = r0 + rloc;
        float4 xv = (rr < nrows) ? X4[(size_t)rr * 32 + kq]
                                 : make_float4(0.f, 0.f, 0.f, 0.f);
        int ks = kq >> 3, g = (kq >> 1) & 3, half = kq & 1;
        int wvd = rloc >> 4, ln = (rloc & 15) + 16 * g;
        ushort4 p;
        p.x = f2h(xv.x); p.y = f2h(xv.y); p.z = f2h(xv.z); p.w = f2h(xv.w);
        *(ushort4*)&xp[(((ks * 4 + wvd) * 64 + ln) << 3) + half * 4] = p;
    }
    __syncthreads();
    f32x4 acc[8];
#pragma unroll
    for (int c = 0; c < 8; ++c) acc[c] = (f32x4){0.f, 0.f, 0.f, 0.f};
#pragma unroll
    for (int ks = 0; ks < 4; ++ks) {
        f16x8 a = *reinterpret_cast<f16x8*>(&xp[((ks * 4 + wv) * 64 + lane) << 3]);
#pragma unroll
        for (int ct = 0; ct < 8; ++ct) {
            f16x8 b = *reinterpret_cast<const f16x8*>(pw + ((size_t)((ks * 8 + ct) * 64 + lane) << 3));
            acc[ct] = __builtin_amdgcn_mfma_f32_16x16x32_f16(a, b, acc[ct], 0, 0, 0);
        }
    }
    float dv[4];
#pragma unroll
    for (int r = 0; r < 4; ++r) {
        int m = r0 + wv * 16 + 4 * (lane >> 4) + r;
        dv[r] = (m < nrows) ? dinv[m] : 0.f;
    }
    __syncthreads();
#pragma unroll
    for (int ct = 0; ct < 8; ++ct)
#pragma unroll
        for (int r = 0; r < 4; ++r) {
            int row_local = wv * 16 + 4 * (lane >> 4) + r;
            int colb = ct * 32 + (lane & 15) * 2;
            int byte = row_local * 256 + (colb ^ swz(row_local));
            xp[byte >> 1] = f2h(acc[ct][r] * dv[r]);
        }
    __syncthreads();
#pragma unroll
    for (int p = 0; p < 4; ++p) {
        int row_local = t >> 2;
        int chunk = (t & 3) + 4 * p;
        int byte = row_local * 256 + ((chunk * 16) ^ swz(row_local));
        uint4 val = *reinterpret_cast<uint4*>(&xp[byte >> 1]);
        int rr = r0 + row_local;
        if (rr < nrows) ((uint4*)hp)[(size_t)rr * 16 + chunk] = val;
    }
}

// ---------- MFMA GEMM (f16 input): hp = f16((Xh @ W) * dinv) ----------

__global__ __launch_bounds__(256, 2) void k_gemm_f16(const u16* __restrict__ Xh,
                                                     const u16* __restrict__ pw,
                                                     const float* __restrict__ dinv,
                                                     u16* __restrict__ hp, int nrows) {
    __shared__ u16 xp[8192];
    const int t = threadIdx.x, lane = t & 63, wv = t >> 6;
    const int r0 = blockIdx.x * 64;
    const uint4* X16 = (const uint4*)Xh;
#pragma unroll
    for (int it = 0; it < 4; ++it) {
        int idx = it * 256 + t;          // 64 rows x 16 16B-chunks
        int rloc = idx >> 4, c = idx & 15;
        int rr = r0 + rloc;
        uint4 v = (rr < nrows) ? X16[(size_t)rr * 16 + c]
                               : make_uint4(0u, 0u, 0u, 0u);
        int ks = c >> 2, g = c & 3;
        int wvd = rloc >> 4, ln = (rloc & 15) + 16 * g;
        *(uint4*)&xp[((ks * 4 + wvd) * 64 + ln) << 3] = v;
    }
    __syncthreads();
    f32x4 acc[8];
#pragma unroll
    for (int c = 0; c < 8; ++c) acc[c] = (f32x4){0.f, 0.f, 0.f, 0.f};
#pragma unroll
    for (int ks = 0; ks < 4; ++ks) {
        f16x8 a = *reinterpret_cast<f16x8*>(&xp[((ks * 4 + wv) * 64 + lane) << 3]);
#pragma unroll
        for (int ct = 0; ct < 8; ++ct) {
            f16x8 b = *reinterpret_cast<const f16x8*>(pw + ((size_t)((ks * 8 + ct) * 64 + lane) << 3));
            acc[ct] = __builtin_amdgcn_mfma_f32_16x16x32_f16(a, b, acc[ct], 0, 0, 0);
        }
    }
    float dv[4];
#pragma unroll
    for (int r = 0; r < 4; ++r) {
        int m = r0 + wv * 16 + 4 * (lane >> 4) + r;
        dv[r] = (m < nrows) ? dinv[m] : 0.f;
    }
    __syncthreads();
#pragma unroll
    for (int ct = 0; ct < 8; ++ct)
#pragma unroll
        for (int r = 0; r < 4; ++r) {
            int row_local = wv * 16 + 4 * (lane >> 4) + r;
            int colb = ct * 32 + (lane & 15) * 2;
            int byte = row_local * 256 + (colb ^ swz(row_local));
            xp[byte >> 1] = f2h(acc[ct][r] * dv[r]);
        }
    __syncthreads();
#pragma unroll
    for (int p = 0; p < 4; ++p) {
        int row_local = t >> 2;
        int chunk = (t & 3) + 4 * p;
        int byte = row_local * 256 + ((chunk * 16) ^ swz(row_local));
        uint4 val = *reinterpret_cast<uint4*>(&xp[byte >> 1]);
        int rr = r0 + row_local;
        if (rr < nrows) ((uint4*)hp)[(size_t)rr * 16 + chunk] = val;
    }
}

// ---------- aggregation (wide): wave = 1 node, 16 lanes/edge, uint4 loads ----------
// lane: slot = lane>>4 (edge slot 0..3), colg = lane&15 (16B column group)
// outh[v] = f16(relu(dinv[v]*(hp[v] + sum hp[s]) + b))

__global__ __launch_bounds__(256) void k_agg(const uint32* __restrict__ hp,
                                             const uint32* __restrict__ packed,
                                             const u16* __restrict__ csr,
                                             const float* __restrict__ dinv,
                                             const float* __restrict__ bias,
                                             uint32* __restrict__ outh) {
    const int lane = threadIdx.x & 63;
    const int v = blockIdx.x * 4 + (threadIdx.x >> 6);
    if (v >= NN) return;
    const int slot = lane >> 4, colg = lane & 15;
    const uint4* hp16 = (const uint4*)hp;

    float acc[8];
#pragma unroll
    for (int j = 0; j < 8; ++j) acc[j] = 0.f;

    // self-loop: counted once (slot 0 only, pre-reduction)
    if (slot == 0) {
        uint4 m = hp16[(size_t)v * 16 + colg];
        acc[0] += h2f((u16)(m.x & 0xffffu)); acc[1] += h2f((u16)(m.x >> 16));
        acc[2] += h2f((u16)(m.y & 0xffffu)); acc[3] += h2f((u16)(m.y >> 16));
        acc[4] += h2f((u16)(m.z & 0xffffu)); acc[5] += h2f((u16)(m.z >> 16));
        acc[6] += h2f((u16)(m.w & 0xffffu)); acc[7] += h2f((u16)(m.w >> 16));
    }

    uint32 pk = packed[v];
    const int e0 = (int)(pk & 0xFFFFFu);
    const int end = e0 + (int)(pk >> 20);
    int idx = e0 + slot;

    // 4-deep unroll: 16 edges in flight per wave (4 x uint4 per lane)
    for (; idx + 12 < end; idx += 16) {
        int s0 = csr[idx], s1 = csr[idx + 4], s2 = csr[idx + 8], s3 = csr[idx + 12];
        uint4 m0 = hp16[(size_t)s0 * 16 + colg];
        uint4 m1 = hp16[(size_t)s1 * 16 + colg];
        uint4 m2 = hp16[(size_t)s2 * 16 + colg];
        uint4 m3 = hp16[(size_t)s3 * 16 + colg];
#pragma unroll
        for (int q = 0; q < 4; ++q) {
            uint4 m = (q == 0) ? m0 : (q == 1) ? m1 : (q == 2) ? m2 : m3;
            acc[0] += h2f((u16)(m.x & 0xffffu)); acc[1] += h2f((u16)(m.x >> 16));
            acc[2] += h2f((u16)(m.y & 0xffffu)); acc[3] += h2f((u16)(m.y >> 16));
            acc[4] += h2f((u16)(m.z & 0xffffu)); acc[5] += h2f((u16)(m.z >> 16));
            acc[6] += h2f((u16)(m.w & 0xffffu)); acc[7] += h2f((u16)(m.w >> 16));
        }
    }
    for (; idx < end; idx += 4) {
        int s = csr[idx];
        uint4 m = hp16[(size_t)s * 16 + colg];
        acc[0] += h2f((u16)(m.x & 0xffffu)); acc[1] += h2f((u16)(m.x >> 16));
        acc[2] += h2f((u16)(m.y & 0xffffu)); acc[3] += h2f((u16)(m.y >> 16));
        acc[4] += h2f((u16)(m.z & 0xffffu)); acc[5] += h2f((u16)(m.z >> 16));
        acc[6] += h2f((u16)(m.w & 0xffffu)); acc[7] += h2f((u16)(m.w >> 16));
    }

    // reduce across the 4 edge slots (lanes differ only in bit4,bit5)
#pragma unroll
    for (int j = 0; j < 8; ++j) {
        acc[j] += __shfl_xor(acc[j], 16, 64);
        acc[j] += __shfl_xor(acc[j], 32, 64);
    }

    if (slot == 0) {
        float dvv = dinv[v];
        float4 ba = ((const float4*)bias)[colg * 2];
        float4 bb = ((const float4*)bias)[colg * 2 + 1];
        uint4 o;
        o.x = pkh2(fmaxf(acc[0] * dvv + ba.x, 0.f), fmaxf(acc[1] * dvv + ba.y, 0.f));
        o.y = pkh2(fmaxf(acc[2] * dvv + ba.z, 0.f), fmaxf(acc[3] * dvv + ba.w, 0.f));
        o.z = pkh2(fmaxf(acc[4] * dvv + bb.x, 0.f), fmaxf(acc[5] * dvv + bb.y, 0.f));
        o.w = pkh2(fmaxf(acc[6] * dvv + bb.z, 0.f), fmaxf(acc[7] * dvv + bb.w, 0.f));
        ((uint4*)outh)[(size_t)v * 16 + colg] = o;
    }
}

// ---------- pooling stage 1: f16 in, fp32 segment-sum into pooled[64][128] ----------

__global__ __launch_bounds__(256) void k_pool1(const uint32* __restrict__ h,
                                               const int* __restrict__ batch,
                                               float* __restrict__ pooled) {
    __shared__ int bl[256];
    const int row0 = blockIdx.x * 256;
    const int rend = min(row0 + 256, NN);
    const int nrows = rend - row0;
    for (int i = threadIdx.x; i < nrows; i += 256) bl[i] = batch[row0 + i];
    __syncthreads();
    const int col2 = threadIdx.x & 63;
    const int rp   = threadIdx.x >> 6;
    float2 acc = make_float2(0.f, 0.f);
    int curg = -1;
    for (int i = rp; i < nrows; i += 4) {
        int g = bl[i];
        if (g != curg) {
            if (curg >= 0) {
                atomicAdd(&pooled[curg * 128 + 2 * col2], acc.x);
                atomicAdd(&pooled[curg * 128 + 2 * col2 + 1], acc.y);
            }
            acc = make_float2(0.f, 0.f);
            curg = g;
        }
        acc_h2(acc, h[(size_t)(row0 + i) * 64 + col2]);
    }
    if (curg >= 0) {
        atomicAdd(&pooled[curg * 128 + 2 * col2], acc.x);
        atomicAdd(&pooled[curg * 128 + 2 * col2 + 1], acc.y);
    }
}

// ---------- pooling stage 2: mean + linear head ----------

__global__ __launch_bounds__(256) void k_head(const float* __restrict__ pooled,
                                              const int* __restrict__ batch,
                                              const float* __restrict__ Wl,
                                              const float* __restrict__ bl_,
                                              float* __restrict__ out) {
    int g = blockIdx.x, t = threadIdx.x;
    __shared__ int se[2];
    __shared__ float pm[128];
    __shared__ float part[256];
    if (t < 2) {
        int target = g + t;
        int lo = 0, hi = NN;
        while (lo < hi) {
            int mid = (lo + hi) >> 1;
            if (batch[mid] < target) lo = mid + 1; else hi = mid;
        }
        se[t] = lo;
    }
    __syncthreads();
    int cntg = se[1] - se[0];
    float inv = 1.f / (float)(cntg > 0 ? cntg : 1);
    if (t < 128) pm[t] = pooled[g * 128 + t] * inv;
    __syncthreads();
    int col = t & 63, kh = t >> 6;
    float o = 0.f;
    for (int k = kh * 32; k < kh * 32 + 32; ++k) o += pm[k] * Wl[k * OD + col];
    part[t] = o; __syncthreads();
    if (t < OD)
        out[g * OD + t] = part[t] + part[t + 64] + part[t + 128] + part[t + 192] + bl_[t];
}

// ---------- launcher ----------

extern "C" void kernel_launch(void* const* d_in, const int* in_sizes, int n_in,
                              void* d_out, int out_size, void* d_ws, size_t ws_size,
                              hipStream_t stream) {
    const float* x   = (const float*)d_in[0];
    const int*   ei  = (const int*)d_in[1];
    const int*   bat = (const int*)d_in[2];
    const float* W1  = (const float*)d_in[3];
    const float* b1  = (const float*)d_in[4];
    const float* W2  = (const float*)d_in[5];
    const float* b2  = (const float*)d_in[6];
    const float* Wl  = (const float*)d_in[7];
    const float* bl  = (const float*)d_in[8];
    float* out = (float*)d_out;
    const int* src = ei;
    const int* dst = ei + NE;

    char* w = (char*)d_ws;
    size_t off = 0;
    auto alloc = [&](size_t bytes) -> char* {
        char* p = w + off;
        off = (off + bytes + 255) & ~(size_t)255;
        return p;
    };
    float*  dinv        = (float*)alloc(NN * 4);
    uint32* packed      = (uint32*)alloc(NN * 4);
    int*    bucket_fill = (int*)alloc(NBUCK * 4);
    float*  pooled      = (float*)alloc(NG * HD * 4);
    u16*    pw1         = (u16*)alloc(2048 * 16);
    u16*    pw2         = (u16*)alloc(2048 * 16);
    uint32* grec        = (uint32*)alloc((size_t)NBUCK * CSR_CAP * 4);
    u16*    csr         = (u16*)alloc((size_t)NBUCK * CSR_CAP * 2);
    u16*    hp          = (u16*)alloc((size_t)NN * HD * 2);   // f16 h'
    u16*    h2          = (u16*)alloc((size_t)NN * HD * 2);   // f16 layer output

    k_prep<<<17, 256, 0, stream>>>(W1, W2, pw1, pw2, bucket_fill, pooled);
    k_scatter<<<SBLOCKS, 256, 0, stream>>>(src, dst, bucket_fill, grec);
    k_csr<<<NBUCK, 256, 0, stream>>>(grec, bucket_fill, packed, dinv, csr);

    // conv1
    k_gemm_f32<<<GEMM_BLOCKS, 256, 0, stream>>>(x, pw1, dinv, hp, NN);
    k_agg<<<(NN + 3) / 4, 256, 0, stream>>>((const uint32*)hp, packed, csr, dinv, b1, (uint32*)h2);
    // conv2
    k_gemm_f16<<<GEMM_BLOCKS, 256, 0, stream>>>(h2, pw2, dinv, hp, NN);
    k_agg<<<(NN + 3) / 4, 256, 0, stream>>>((const uint32*)hp, packed, csr, dinv, b2, (uint32*)h2);
    // pool + head
    k_pool1<<<(NN + 255) / 256, 256, 0, stream>>>((const uint32*)h2, bat, pooled);
    k_head<<<NG, 256, 0, stream>>>(pooled, bat, Wl, bl, out);
}